// Round 6
// baseline (218.866 us; speedup 1.0000x reference)
//
#include <hip/hip_runtime.h>
#include <hip/hip_bf16.h>

typedef __attribute__((ext_vector_type(8))) short short8;
typedef __attribute__((ext_vector_type(4))) float floatx4;
typedef unsigned int u32;

#define NN 4096

static __device__ __forceinline__ unsigned f2bf_rne(float x) {
    union { float f; unsigned u; } v; v.f = x;
    unsigned r = v.u + 0x7fffu + ((v.u >> 16) & 1u);
    return r >> 16;
}
static __device__ __forceinline__ float bf2f(unsigned hi) {
    union { unsigned u; float f; } v; v.u = hi << 16; return v.f;
}

// ---- prep (fused wc, ROUND-0 PROVEN): per-block computes Wc=W1@W2, w1*alpha;
// then G = X@Wc (bf16 hi/lo MFMA) -> Gt bf16 [b*64+c][4096]; lv/rv fp32.
__global__ __launch_bounds__(256, 4)
void prep_kernel(const float* __restrict__ X,
                 const float* __restrict__ W1,
                 const float* __restrict__ W2,
                 const float* __restrict__ alpha,
                 unsigned short* __restrict__ Gt,
                 float* __restrict__ lv,
                 float* __restrict__ rv) {
    __shared__ __align__(16) char sm[53248];
    float* W1s  = (float*)sm;                 // [64][68]
    float* W2s  = (float*)(sm + 17408);       // [64][68]
    float* Wcst = (float*)(sm + 34816);       // Wc^T: [n][k] stride 68
    float* w1s  = (float*)(sm + 52224);       // [128]
    float* als  = (float*)(sm + 52736);       // [128]
    float* GsT  = (float*)sm;                 // epilogue reuse: [64][68]

    const int t = threadIdx.x;
    const int row0 = blockIdx.x * 64;         // flat b*N + n
    const int b = row0 >> 12, n0 = row0 & (NN - 1);
    const int w = t >> 6, lane = t & 63;
    const int m = lane & 15, q = lane >> 4;

    // issue X loads early (consumed much later)
    const int row = row0 + w * 16 + m;
    const float* xp = X + (size_t)row * 64;
    float4 x0 = *(const float4*)(xp + q * 8);
    float4 x1 = *(const float4*)(xp + q * 8 + 4);
    float4 x2 = *(const float4*)(xp + 32 + q * 8);
    float4 x3 = *(const float4*)(xp + 32 + q * 8 + 4);

    #pragma unroll
    for (int s = 0; s < 4; ++s) {
        int idx = s * 1024 + t * 4;
        int r = idx >> 6, cc = idx & 63;
        *(float4*)&W1s[r * 68 + cc] = *(const float4*)(W1 + idx);
        *(float4*)&W2s[r * 68 + cc] = *(const float4*)(W2 + idx);
    }
    if (t < 128) als[t] = alpha[t];
    __syncthreads();

    // Wc^T: thread (k = t>>2, nq = t&3) computes Wc[k][n], n in [nq*16, nq*16+16)
    {
        const int k = t >> 2, nq = t & 3;
        float acc[16];
        #pragma unroll
        for (int i = 0; i < 16; ++i) acc[i] = 0.f;
        for (int mm = 0; mm < 64; ++mm) {
            float w1v = W1s[k * 68 + mm];
            #pragma unroll
            for (int i = 0; i < 16; ++i)
                acc[i] += w1v * W2s[mm * 68 + nq * 16 + i];
        }
        #pragma unroll
        for (int i = 0; i < 16; ++i)
            Wcst[(nq * 16 + i) * 68 + k] = acc[i];
    }
    if (t < 64) {   // w1a = {W1@aL, W1@aR}
        float sl = 0.f, sr = 0.f;
        for (int cc2 = 0; cc2 < 64; ++cc2) {
            float wv = W1s[t * 68 + cc2];
            sl += wv * als[cc2];
            sr += wv * als[64 + cc2];
        }
        w1s[t] = sl; w1s[64 + t] = sr;
    }
    __syncthreads();

    const float xs[16] = {x0.x,x0.y,x0.z,x0.w, x1.x,x1.y,x1.z,x1.w,
                          x2.x,x2.y,x2.z,x2.w, x3.x,x3.y,x3.z,x3.w};

    // lv/rv fp32
    float pl = 0.f, pr = 0.f;
    #pragma unroll
    for (int ks = 0; ks < 2; ++ks)
        #pragma unroll
        for (int j = 0; j < 8; ++j) {
            int k = ks * 32 + q * 8 + j;
            float xv = xs[ks * 8 + j];
            pl += xv * w1s[k];
            pr += xv * w1s[64 + k];
        }
    pl += __shfl_xor(pl, 16, 64); pl += __shfl_xor(pl, 32, 64);
    pr += __shfl_xor(pr, 16, 64); pr += __shfl_xor(pr, 32, 64);
    if (q == 0) { lv[row] = pl; rv[row] = pr; }

    // bf16 hi/lo A-fragments
    short8 ah[2], al[2];
    #pragma unroll
    for (int ks = 0; ks < 2; ++ks)
        #pragma unroll
        for (int j = 0; j < 8; ++j) {
            float f = xs[ks * 8 + j];
            unsigned hb = f2bf_rne(f);
            float res = f - bf2f(hb);
            ah[ks][j] = (short)hb;
            al[ks][j] = (short)f2bf_rne(res);
        }

    // B-frags from Wcst
    short8 bfr[4][2];
    #pragma unroll
    for (int nt = 0; nt < 4; ++nt)
        #pragma unroll
        for (int ks = 0; ks < 2; ++ks) {
            const float* wp = &Wcst[(nt * 16 + m) * 68 + ks * 32 + q * 8];
            float4 w0 = *(const float4*)wp;
            float4 w1 = *(const float4*)(wp + 4);
            short8 bf;
            bf[0] = (short)f2bf_rne(w0.x); bf[1] = (short)f2bf_rne(w0.y);
            bf[2] = (short)f2bf_rne(w0.z); bf[3] = (short)f2bf_rne(w0.w);
            bf[4] = (short)f2bf_rne(w1.x); bf[5] = (short)f2bf_rne(w1.y);
            bf[6] = (short)f2bf_rne(w1.z); bf[7] = (short)f2bf_rne(w1.w);
            bfr[nt][ks] = bf;
        }

    floatx4 acc[4] = {{0,0,0,0},{0,0,0,0},{0,0,0,0},{0,0,0,0}};
    #pragma unroll
    for (int ks = 0; ks < 2; ++ks)
        #pragma unroll
        for (int nt = 0; nt < 4; ++nt) {
            acc[nt] = __builtin_amdgcn_mfma_f32_16x16x32_bf16(ah[ks], bfr[nt][ks], acc[nt], 0, 0, 0);
            acc[nt] = __builtin_amdgcn_mfma_f32_16x16x32_bf16(al[ks], bfr[nt][ks], acc[nt], 0, 0, 0);
        }

    __syncthreads();    // all Wcst/W1s reads done; sm@0 reused as GsT
    #pragma unroll
    for (int nt = 0; nt < 4; ++nt)
        #pragma unroll
        for (int rg = 0; rg < 4; ++rg)
            GsT[(nt * 16 + m) * 68 + w * 16 + q * 4 + rg] = acc[nt][rg];
    __syncthreads();
    unsigned* Gu = (unsigned*)Gt;
    #pragma unroll
    for (int it2 = 0; it2 < 8; ++it2) {
        int c2 = (t >> 5) + it2 * 8;
        int np = t & 31;
        unsigned lo = f2bf_rne(GsT[c2 * 68 + 2 * np]);
        unsigned hi = f2bf_rne(GsT[c2 * 68 + 2 * np + 1]);
        Gu[(((((size_t)(b * 64 + c2)) << 12) + n0) >> 1) + np] = lo | (hi << 16);
    }
}

// ---- attn_main v6: ONE WAVE per block, ZERO barriers. grid 4096 =
// (it16 256, grp 4, b 4; b fastest so the 4 b-copies of an A-tile dispatch
// adjacently -> L2/L3 serve 3/4 of A re-reads). Each wave owns 16 i-rows x
// 1024 j and stages its own 64ch x 32j G-chunk into WAVE-PRIVATE
// double-buffered LDS (64 B/lane/chunk) -> no cross-wave sharing, no
// __syncthreads; all ordering is same-wave vmcnt/lgkmcnt (compiler-
// inserted, race-free by construction). 16 blocks/CU (9216 B LDS each,
// 4 waves/SIMD) give the SIMD 4 independent waves to hide global latency.
// E in-register consumer layout + VALU dsum (v4-proven); depth-1 named-reg
// prefetch (use-then-reload, 1-iter latency distance) for G-stage and A/rv.
__global__ __launch_bounds__(64, 4)
void attn_main(const float* __restrict__ A,
               const unsigned short* __restrict__ Gt,
               const float* __restrict__ lv,
               const float* __restrict__ rv,
               float* __restrict__ pout) {
    __shared__ __align__(16) unsigned short Gs[2][64 * 36];   // wave-private dbuf

    const int bx = blockIdx.x;
    const int b    = bx & 3;
    const int grp  = (bx >> 2) & 3;
    const int it16 = bx >> 4;
    const int i0   = it16 * 16;
    const int t = threadIdx.x;                // 0..63, one wave
    const int m = t & 15, q = t >> 4;

    const float* aRow = A + (size_t)(i0 + m) * NN + grp * 1024 + q * 8;
    const float* rvp  = rv + (size_t)b * NN + grp * 1024 + q * 8;
    // staging: lane stages channel t, 64 B per chunk (4 x short8)
    const unsigned short* gSt = Gt + (((size_t)(b * 64 + t)) << 12) + grp * 1024;

    const float li = lv[b * NN + i0 + m] * 1.44269504f;   // fold log2e
    const float li001 = li * 0.01f;

    const bool diag_grp = ((i0 >> 10) == grp);
    const int jd = (i0 + m) - grp * 1024;

    // prologue: chunk 0 -> regs -> buf0; chunk 1 -> regs; A/rv chunk 0
    short8 sg0 = *(const short8*)(gSt);
    short8 sg1 = *(const short8*)(gSt + 8);
    short8 sg2 = *(const short8*)(gSt + 16);
    short8 sg3 = *(const short8*)(gSt + 24);
    *(short8*)&Gs[0][t * 36 + 0]  = sg0;
    *(short8*)&Gs[0][t * 36 + 8]  = sg1;
    *(short8*)&Gs[0][t * 36 + 16] = sg2;
    *(short8*)&Gs[0][t * 36 + 24] = sg3;
    sg0 = *(const short8*)(gSt + 32);
    sg1 = *(const short8*)(gSt + 40);
    sg2 = *(const short8*)(gSt + 48);
    sg3 = *(const short8*)(gSt + 56);
    float4 a0 = *(const float4*)(aRow);
    float4 a1 = *(const float4*)(aRow + 4);
    float4 r0 = *(const float4*)(rvp);
    float4 r1 = *(const float4*)(rvp + 4);

    floatx4 acc0 = {0,0,0,0}, acc1 = {0,0,0,0}, acc2 = {0,0,0,0}, acc3 = {0,0,0,0};
    float dsum = 0.f;

    #pragma unroll 2
    for (int cc = 0; cc < 32; ++cc) {
        // write chunk cc+1 (held in sg*) into buf[(cc+1)&1]
        {
            unsigned short* wp = &Gs[(cc + 1) & 1][t * 36];
            *(short8*)(wp + 0)  = sg0;
            *(short8*)(wp + 8)  = sg1;
            *(short8*)(wp + 16) = sg2;
            *(short8*)(wp + 24) = sg3;
        }
        // reload sg* with chunk cc+2 (WAR after the writes consumed them)
        { const int jn = (cc + 2 < 32) ? (cc + 2) * 32 : 0;
          sg0 = *(const short8*)(gSt + jn);
          sg1 = *(const short8*)(gSt + jn + 8);
          sg2 = *(const short8*)(gSt + jn + 16);
          sg3 = *(const short8*)(gSt + jn + 24); }

        // ---- E in consumer layout for chunk cc (A/rv regs loaded last iter) ----
        float aa[8] = {a0.x, a0.y, a0.z, a0.w, a1.x, a1.y, a1.z, a1.w};
        if (diag_grp && ((jd >> 5) == cc)) {              // adj diag := 1
            const int dd = jd - (cc * 32 + q * 8);
            #pragma unroll
            for (int e = 0; e < 8; ++e) if (dd == e) aa[e] = 1.0f;
        }
        const float rr[8] = {r0.x, r0.y, r0.z, r0.w, r1.x, r1.y, r1.z, r1.w};
        unsigned up[8];
        #pragma unroll
        for (int e = 0; e < 8; ++e) {
            float s = fmaxf(li * rr[e], li001 * rr[e]);   // leaky(li*r)
            float ev = __builtin_amdgcn_exp2f(s) * aa[e];
            unsigned u = __float_as_uint(ev) + 0x8000u;
            up[e] = u;
            dsum += __uint_as_float(u & 0xffff0000u);     // den = same bf16 vals
        }
        union { unsigned u[4]; short8 s8; } cv;
        cv.u[0] = __builtin_amdgcn_perm(up[1], up[0], 0x07060302u);
        cv.u[1] = __builtin_amdgcn_perm(up[3], up[2], 0x07060302u);
        cv.u[2] = __builtin_amdgcn_perm(up[5], up[4], 0x07060302u);
        cv.u[3] = __builtin_amdgcn_perm(up[7], up[6], 0x07060302u);
        const short8 afr = cv.s8;

        // reload A/rv with chunk cc+1 (used next iteration)
        { const int jn = (cc + 1 < 32) ? (cc + 1) * 32 : 0;
          a0 = *(const float4*)(aRow + jn);
          a1 = *(const float4*)(aRow + jn + 4);
          r0 = *(const float4*)(rvp + jn);
          r1 = *(const float4*)(rvp + jn + 4); }

        // B-frags from buf[cc&1] (written by THIS wave last iteration)
        {
            const unsigned short* rp = &Gs[cc & 1][0];
            const short8 b0 = *(const short8*)&rp[( m) * 36 + q * 8];
            const short8 b1 = *(const short8*)&rp[(16 + m) * 36 + q * 8];
            const short8 b2 = *(const short8*)&rp[(32 + m) * 36 + q * 8];
            const short8 b3 = *(const short8*)&rp[(48 + m) * 36 + q * 8];
            acc0 = __builtin_amdgcn_mfma_f32_16x16x32_bf16(afr, b0, acc0, 0, 0, 0);
            acc1 = __builtin_amdgcn_mfma_f32_16x16x32_bf16(afr, b1, acc1, 0, 0, 0);
            acc2 = __builtin_amdgcn_mfma_f32_16x16x32_bf16(afr, b2, acc2, 0, 0, 0);
            acc3 = __builtin_amdgcn_mfma_f32_16x16x32_bf16(afr, b3, acc3, 0, 0, 0);
        }
    }

    // den: reduce over the 4 q-lanes of each row
    dsum += __shfl_xor(dsum, 16, 64);
    dsum += __shfl_xor(dsum, 32, 64);

    // ---- epilogue: direct f32 partial store [16 rows][68] ----
    float* pb = pout + (size_t)bx * (16 * 68);
    #pragma unroll
    for (int nt = 0; nt < 4; ++nt) {
        floatx4 av = nt == 0 ? acc0 : nt == 1 ? acc1 : nt == 2 ? acc2 : acc3;
        #pragma unroll
        for (int rg = 0; rg < 4; ++rg)
            pb[(q * 4 + rg) * 68 + nt * 16 + m] = av[rg];
    }
    if (q == 0) pb[m * 68 + 64] = dsum;
}

// ---- attn_reduce: grid 256 = (it64, b), 256 thr. Sums the 4 grp partials
// per output row, divides by summed den, writes out.
__global__ __launch_bounds__(256, 4)
void attn_reduce(const float* __restrict__ pout,
                 float* __restrict__ out) {
    const int bx = blockIdx.x;
    const int it64 = bx & 63, b = bx >> 6;
    const int t = threadIdx.x;
    const int r64 = t >> 2, quad = t & 3;

    const int it16 = (it64 << 2) + (r64 >> 4);
    const int rr = r64 & 15;

    const float* base0 = pout + ((size_t)(((it16 * 4) + 0) * 4 + b)) * 1088 + rr * 68;
    const float* base1 = pout + ((size_t)(((it16 * 4) + 1) * 4 + b)) * 1088 + rr * 68;
    const float* base2 = pout + ((size_t)(((it16 * 4) + 2) * 4 + b)) * 1088 + rr * 68;
    const float* base3 = pout + ((size_t)(((it16 * 4) + 3) * 4 + b)) * 1088 + rr * 68;

    float den = base0[64] + base1[64] + base2[64] + base3[64];
    const float rinv = 1.0f / den;

    float* op = out + (((size_t)(b * NN + it64 * 64 + r64)) << 6) + quad * 16;
    #pragma unroll
    for (int f = 0; f < 4; ++f) {
        const float4 v0 = *(const float4*)&base0[quad * 16 + f * 4];
        const float4 v1 = *(const float4*)&base1[quad * 16 + f * 4];
        const float4 v2 = *(const float4*)&base2[quad * 16 + f * 4];
        const float4 v3 = *(const float4*)&base3[quad * 16 + f * 4];
        float4 o;
        o.x = (v0.x + v1.x + v2.x + v3.x) * rinv;
        o.y = (v0.y + v1.y + v2.y + v3.y) * rinv;
        o.z = (v0.z + v1.z + v2.z + v3.z) * rinv;
        o.w = (v0.w + v1.w + v2.w + v3.w) * rinv;
        *(float4*)(op + f * 4) = o;
    }
}

extern "C" void kernel_launch(void* const* d_in, const int* in_sizes, int n_in,
                              void* d_out, int out_size, void* d_ws, size_t ws_size,
                              hipStream_t stream) {
    const float* X     = (const float*)d_in[0];
    const float* A     = (const float*)d_in[1];
    const float* W1    = (const float*)d_in[2];
    const float* W2    = (const float*)d_in[3];
    const float* alpha = (const float*)d_in[4];
    float* out = (float*)d_out;

    char* ws = (char*)d_ws;
    unsigned short* Gt = (unsigned short*)(ws);            // 2 MiB
    float* lvp  = (float*)(ws + 2097152);                  // 64 KiB
    float* rvp  = (float*)(ws + 2097152 + 65536);          // 64 KiB
    float* pout = (float*)(ws + 2097152 + 131072);         // 4096*1088*4 = 17.8 MiB

    prep_kernel<<<256, 256, 0, stream>>>(X, W1, W2, alpha, Gt, lvp, rvp);
    attn_main<<<4096, 64, 0, stream>>>(A, Gt, lvp, rvp, pout);
    attn_reduce<<<256, 256, 0, stream>>>(pout, out);
}

// Round 7
// 212.106 us; speedup vs baseline: 1.0319x; 1.0319x over previous
//
#include <hip/hip_runtime.h>
#include <hip/hip_bf16.h>

typedef __attribute__((ext_vector_type(8))) short short8;
typedef __attribute__((ext_vector_type(4))) float floatx4;
typedef unsigned int u32;

#define NN 4096

static __device__ __forceinline__ unsigned f2bf_rne(float x) {
    union { float f; unsigned u; } v; v.f = x;
    unsigned r = v.u + 0x7fffu + ((v.u >> 16) & 1u);
    return r >> 16;
}
static __device__ __forceinline__ float bf2f(unsigned hi) {
    union { unsigned u; float f; } v; v.u = hi << 16; return v.f;
}

// ---- prep (fused wc, round-0 proven): per-block computes Wc=W1@W2, w1*alpha;
// then G = X@Wc (bf16 hi/lo MFMA). NEW: Gt written in TILED layout
// Gt2[b][jc=128][ch=64][j32=32] bf16 so one MFMA chunk (64ch x 32j) is a
// contiguous 4 KB tile -> attn B-frag loads become perfectly coalesced.
__global__ __launch_bounds__(256, 4)
void prep_kernel(const float* __restrict__ X,
                 const float* __restrict__ W1,
                 const float* __restrict__ W2,
                 const float* __restrict__ alpha,
                 unsigned short* __restrict__ Gt,
                 float* __restrict__ lv,
                 float* __restrict__ rv) {
    __shared__ __align__(16) char sm[53248];
    float* W1s  = (float*)sm;                 // [64][68]
    float* W2s  = (float*)(sm + 17408);       // [64][68]
    float* Wcst = (float*)(sm + 34816);       // Wc^T: [n][k] stride 68
    float* w1s  = (float*)(sm + 52224);       // [128]
    float* als  = (float*)(sm + 52736);       // [128]
    float* GsT  = (float*)sm;                 // epilogue reuse: [64][68]

    const int t = threadIdx.x;
    const int row0 = blockIdx.x * 64;         // flat b*N + n
    const int b = row0 >> 12, n0 = row0 & (NN - 1);
    const int w = t >> 6, lane = t & 63;
    const int m = lane & 15, q = lane >> 4;

    // issue X loads early (consumed much later)
    const int row = row0 + w * 16 + m;
    const float* xp = X + (size_t)row * 64;
    float4 x0 = *(const float4*)(xp + q * 8);
    float4 x1 = *(const float4*)(xp + q * 8 + 4);
    float4 x2 = *(const float4*)(xp + 32 + q * 8);
    float4 x3 = *(const float4*)(xp + 32 + q * 8 + 4);

    #pragma unroll
    for (int s = 0; s < 4; ++s) {
        int idx = s * 1024 + t * 4;
        int r = idx >> 6, cc = idx & 63;
        *(float4*)&W1s[r * 68 + cc] = *(const float4*)(W1 + idx);
        *(float4*)&W2s[r * 68 + cc] = *(const float4*)(W2 + idx);
    }
    if (t < 128) als[t] = alpha[t];
    __syncthreads();

    // Wc^T: thread (k = t>>2, nq = t&3) computes Wc[k][n], n in [nq*16, nq*16+16)
    {
        const int k = t >> 2, nq = t & 3;
        float acc[16];
        #pragma unroll
        for (int i = 0; i < 16; ++i) acc[i] = 0.f;
        for (int mm = 0; mm < 64; ++mm) {
            float w1v = W1s[k * 68 + mm];
            #pragma unroll
            for (int i = 0; i < 16; ++i)
                acc[i] += w1v * W2s[mm * 68 + nq * 16 + i];
        }
        #pragma unroll
        for (int i = 0; i < 16; ++i)
            Wcst[(nq * 16 + i) * 68 + k] = acc[i];
    }
    if (t < 64) {   // w1a = {W1@aL, W1@aR}
        float sl = 0.f, sr = 0.f;
        for (int cc2 = 0; cc2 < 64; ++cc2) {
            float wv = W1s[t * 68 + cc2];
            sl += wv * als[cc2];
            sr += wv * als[64 + cc2];
        }
        w1s[t] = sl; w1s[64 + t] = sr;
    }
    __syncthreads();

    const float xs[16] = {x0.x,x0.y,x0.z,x0.w, x1.x,x1.y,x1.z,x1.w,
                          x2.x,x2.y,x2.z,x2.w, x3.x,x3.y,x3.z,x3.w};

    // lv/rv fp32
    float pl = 0.f, pr = 0.f;
    #pragma unroll
    for (int ks = 0; ks < 2; ++ks)
        #pragma unroll
        for (int j = 0; j < 8; ++j) {
            int k = ks * 32 + q * 8 + j;
            float xv = xs[ks * 8 + j];
            pl += xv * w1s[k];
            pr += xv * w1s[64 + k];
        }
    pl += __shfl_xor(pl, 16, 64); pl += __shfl_xor(pl, 32, 64);
    pr += __shfl_xor(pr, 16, 64); pr += __shfl_xor(pr, 32, 64);
    if (q == 0) { lv[row] = pl; rv[row] = pr; }

    // bf16 hi/lo A-fragments
    short8 ah[2], al[2];
    #pragma unroll
    for (int ks = 0; ks < 2; ++ks)
        #pragma unroll
        for (int j = 0; j < 8; ++j) {
            float f = xs[ks * 8 + j];
            unsigned hb = f2bf_rne(f);
            float res = f - bf2f(hb);
            ah[ks][j] = (short)hb;
            al[ks][j] = (short)f2bf_rne(res);
        }

    // B-frags from Wcst
    short8 bfr[4][2];
    #pragma unroll
    for (int nt = 0; nt < 4; ++nt)
        #pragma unroll
        for (int ks = 0; ks < 2; ++ks) {
            const float* wp = &Wcst[(nt * 16 + m) * 68 + ks * 32 + q * 8];
            float4 w0 = *(const float4*)wp;
            float4 w1 = *(const float4*)(wp + 4);
            short8 bf;
            bf[0] = (short)f2bf_rne(w0.x); bf[1] = (short)f2bf_rne(w0.y);
            bf[2] = (short)f2bf_rne(w0.z); bf[3] = (short)f2bf_rne(w0.w);
            bf[4] = (short)f2bf_rne(w1.x); bf[5] = (short)f2bf_rne(w1.y);
            bf[6] = (short)f2bf_rne(w1.z); bf[7] = (short)f2bf_rne(w1.w);
            bfr[nt][ks] = bf;
        }

    floatx4 acc[4] = {{0,0,0,0},{0,0,0,0},{0,0,0,0},{0,0,0,0}};
    #pragma unroll
    for (int ks = 0; ks < 2; ++ks)
        #pragma unroll
        for (int nt = 0; nt < 4; ++nt) {
            acc[nt] = __builtin_amdgcn_mfma_f32_16x16x32_bf16(ah[ks], bfr[nt][ks], acc[nt], 0, 0, 0);
            acc[nt] = __builtin_amdgcn_mfma_f32_16x16x32_bf16(al[ks], bfr[nt][ks], acc[nt], 0, 0, 0);
        }

    __syncthreads();    // all Wcst/W1s reads done; sm@0 reused as GsT
    #pragma unroll
    for (int nt = 0; nt < 4; ++nt)
        #pragma unroll
        for (int rg = 0; rg < 4; ++rg)
            GsT[(nt * 16 + m) * 68 + w * 16 + q * 4 + rg] = acc[nt][rg];
    __syncthreads();
    unsigned* Gu = (unsigned*)Gt;
    #pragma unroll
    for (int it2 = 0; it2 < 8; ++it2) {
        int c2 = (t >> 5) + it2 * 8;
        int np = t & 31;
        unsigned lo = f2bf_rne(GsT[c2 * 68 + 2 * np]);
        unsigned hi = f2bf_rne(GsT[c2 * 68 + 2 * np + 1]);
        // tiled store: j = n0 + 2*np; jc = j>>5; u32 idx = ((b*128+jc)*64+c2)*16 + (np&15)
        const int jc = (n0 >> 5) + (np >> 4);
        Gu[((size_t)(b * 128 + jc) * 64 + c2) * 16 + (np & 15)] = lo | (hi << 16);
    }
}

// ---- attn_main v7: 1-wave blocks, ZERO barriers, ZERO LDS. grid 4096 =
// (it16 256, grp 4, b 4; b fastest for L3 reuse of A). B-fragments loaded
// DIRECTLY from the tiled Gt2: lane (m,q) frag nt reads 16 B at tile offset
// (nt*16+m)*32+q*8 -> the 64 lanes tile 1 KB contiguously = fully-coalesced
// 16-line dwordx4 (v6's staging was a 64-line gather x4/iter -> TA-bound).
// Gt2 tiles are L2-hot (reused by all 256 it16-blocks). A loads are already
// line-optimal (16 rows x 64 B). Depth-2 named prefetch (even/odd sets) for
// A/rv (HBM latency), depth-1 reload-after-use for B (L2 latency). E-gen in
// consumer layout + VALU dsum (v4-proven, bit-identical math).
__global__ __launch_bounds__(64, 4)
void attn_main(const float* __restrict__ A,
               const unsigned short* __restrict__ Gt2,
               const float* __restrict__ lv,
               const float* __restrict__ rv,
               float* __restrict__ pout) {
    const int bx = blockIdx.x;
    const int b    = bx & 3;
    const int grp  = (bx >> 2) & 3;
    const int it16 = bx >> 4;
    const int i0   = it16 * 16;
    const int t = threadIdx.x;                // 0..63, one wave
    const int m = t & 15, q = t >> 4;

    const float* aRow = A + (size_t)(i0 + m) * NN + grp * 1024 + q * 8;
    const float* rvp  = rv + (size_t)b * NN + grp * 1024 + q * 8;
    // lane's B-frag base inside tile; tile cc at +cc*2048, frag nt at +nt*512
    const unsigned short* gT = Gt2 + (size_t)(b * 128 + grp * 32) * 2048 + m * 32 + q * 8;

    const float li = lv[b * NN + i0 + m] * 1.44269504f;   // fold log2e
    const float li001 = li * 0.01f;
    const bool diag_grp = ((i0 >> 10) == grp);
    const int jd = (i0 + m) - grp * 1024;

    // depth-2 prefetch A/rv (set A = chunk 0, set B = chunk 1); B-frags chunk 0
    float4 a0A = *(const float4*)(aRow);
    float4 a1A = *(const float4*)(aRow + 4);
    float4 r0A = *(const float4*)(rvp);
    float4 r1A = *(const float4*)(rvp + 4);
    float4 a0B = *(const float4*)(aRow + 32);
    float4 a1B = *(const float4*)(aRow + 36);
    float4 r0B = *(const float4*)(rvp + 32);
    float4 r1B = *(const float4*)(rvp + 36);
    short8 bf0 = *(const short8*)(gT);
    short8 bf1 = *(const short8*)(gT + 512);
    short8 bf2 = *(const short8*)(gT + 1024);
    short8 bf3 = *(const short8*)(gT + 1536);

    floatx4 acc0 = {0,0,0,0}, acc1 = {0,0,0,0}, acc2 = {0,0,0,0}, acc3 = {0,0,0,0};
    float dsum = 0.f;

    auto genE = [&](float4 a0, float4 a1, float4 r0, float4 r1, int chunk) -> short8 {
        float aa[8] = {a0.x, a0.y, a0.z, a0.w, a1.x, a1.y, a1.z, a1.w};
        if (diag_grp && ((jd >> 5) == chunk)) {           // adj diag := 1
            const int dd = jd - (chunk * 32 + q * 8);
            #pragma unroll
            for (int e = 0; e < 8; ++e) if (dd == e) aa[e] = 1.0f;
        }
        const float rr[8] = {r0.x, r0.y, r0.z, r0.w, r1.x, r1.y, r1.z, r1.w};
        unsigned up[8];
        #pragma unroll
        for (int e = 0; e < 8; ++e) {
            float s = fmaxf(li * rr[e], li001 * rr[e]);   // leaky(li*r)
            float ev = __builtin_amdgcn_exp2f(s) * aa[e];
            unsigned u = __float_as_uint(ev) + 0x8000u;
            up[e] = u;
            dsum += __uint_as_float(u & 0xffff0000u);     // den = same bf16 vals
        }
        union { unsigned u[4]; short8 s8; } cv;
        cv.u[0] = __builtin_amdgcn_perm(up[1], up[0], 0x07060302u);
        cv.u[1] = __builtin_amdgcn_perm(up[3], up[2], 0x07060302u);
        cv.u[2] = __builtin_amdgcn_perm(up[5], up[4], 0x07060302u);
        cv.u[3] = __builtin_amdgcn_perm(up[7], up[6], 0x07060302u);
        return cv.s8;
    };

    for (int cc = 0; cc < 32; cc += 2) {
        // ---- even: chunk cc (A/rv set A; B-frags hold chunk cc) ----
        {
            const short8 afr = genE(a0A, a1A, r0A, r1A, cc);
            { const int jn = (cc + 2 < 32) ? (cc + 2) * 32 : 0;   // reload set A <- cc+2
              a0A = *(const float4*)(aRow + jn);
              a1A = *(const float4*)(aRow + jn + 4);
              r0A = *(const float4*)(rvp + jn);
              r1A = *(const float4*)(rvp + jn + 4); }
            acc0 = __builtin_amdgcn_mfma_f32_16x16x32_bf16(afr, bf0, acc0, 0, 0, 0);
            acc1 = __builtin_amdgcn_mfma_f32_16x16x32_bf16(afr, bf1, acc1, 0, 0, 0);
            acc2 = __builtin_amdgcn_mfma_f32_16x16x32_bf16(afr, bf2, acc2, 0, 0, 0);
            acc3 = __builtin_amdgcn_mfma_f32_16x16x32_bf16(afr, bf3, acc3, 0, 0, 0);
            const unsigned short* gN = gT + (size_t)(cc + 1) * 2048;  // cc+1 <= 31
            bf0 = *(const short8*)(gN);
            bf1 = *(const short8*)(gN + 512);
            bf2 = *(const short8*)(gN + 1024);
            bf3 = *(const short8*)(gN + 1536);
        }
        // ---- odd: chunk cc+1 (A/rv set B; B-frags hold chunk cc+1) ----
        {
            const short8 afr = genE(a0B, a1B, r0B, r1B, cc + 1);
            { const int jn = (cc + 3 < 32) ? (cc + 3) * 32 : 0;   // reload set B <- cc+3
              a0B = *(const float4*)(aRow + jn);
              a1B = *(const float4*)(aRow + jn + 4);
              r0B = *(const float4*)(rvp + jn);
              r1B = *(const float4*)(rvp + jn + 4); }
            acc0 = __builtin_amdgcn_mfma_f32_16x16x32_bf16(afr, bf0, acc0, 0, 0, 0);
            acc1 = __builtin_amdgcn_mfma_f32_16x16x32_bf16(afr, bf1, acc1, 0, 0, 0);
            acc2 = __builtin_amdgcn_mfma_f32_16x16x32_bf16(afr, bf2, acc2, 0, 0, 0);
            acc3 = __builtin_amdgcn_mfma_f32_16x16x32_bf16(afr, bf3, acc3, 0, 0, 0);
            { const int cn = (cc + 2 < 32) ? (cc + 2) : 0;        // reload B-frags <- cc+2
              const unsigned short* gN = gT + (size_t)cn * 2048;
              bf0 = *(const short8*)(gN);
              bf1 = *(const short8*)(gN + 512);
              bf2 = *(const short8*)(gN + 1024);
              bf3 = *(const short8*)(gN + 1536); }
        }
    }

    // den: reduce over the 4 q-lanes of each row
    dsum += __shfl_xor(dsum, 16, 64);
    dsum += __shfl_xor(dsum, 32, 64);

    // ---- epilogue: direct f32 partial store [16 rows][68] ----
    float* pb = pout + (size_t)bx * (16 * 68);
    #pragma unroll
    for (int nt = 0; nt < 4; ++nt) {
        floatx4 av = nt == 0 ? acc0 : nt == 1 ? acc1 : nt == 2 ? acc2 : acc3;
        #pragma unroll
        for (int rg = 0; rg < 4; ++rg)
            pb[(q * 4 + rg) * 68 + nt * 16 + m] = av[rg];
    }
    if (q == 0) pb[m * 68 + 64] = dsum;
}

// ---- attn_reduce: grid 256 = (it64, b), 256 thr. Sums the 4 grp partials
// per output row, divides by summed den, writes out. (v6-verified)
__global__ __launch_bounds__(256, 4)
void attn_reduce(const float* __restrict__ pout,
                 float* __restrict__ out) {
    const int bx = blockIdx.x;
    const int it64 = bx & 63, b = bx >> 6;
    const int t = threadIdx.x;
    const int r64 = t >> 2, quad = t & 3;

    const int it16 = (it64 << 2) + (r64 >> 4);
    const int rr = r64 & 15;

    const float* base0 = pout + ((size_t)(((it16 * 4) + 0) * 4 + b)) * 1088 + rr * 68;
    const float* base1 = pout + ((size_t)(((it16 * 4) + 1) * 4 + b)) * 1088 + rr * 68;
    const float* base2 = pout + ((size_t)(((it16 * 4) + 2) * 4 + b)) * 1088 + rr * 68;
    const float* base3 = pout + ((size_t)(((it16 * 4) + 3) * 4 + b)) * 1088 + rr * 68;

    float den = base0[64] + base1[64] + base2[64] + base3[64];
    const float rinv = 1.0f / den;

    float* op = out + (((size_t)(b * NN + it64 * 64 + r64)) << 6) + quad * 16;
    #pragma unroll
    for (int f = 0; f < 4; ++f) {
        const float4 v0 = *(const float4*)&base0[quad * 16 + f * 4];
        const float4 v1 = *(const float4*)&base1[quad * 16 + f * 4];
        const float4 v2 = *(const float4*)&base2[quad * 16 + f * 4];
        const float4 v3 = *(const float4*)&base3[quad * 16 + f * 4];
        float4 o;
        o.x = (v0.x + v1.x + v2.x + v3.x) * rinv;
        o.y = (v0.y + v1.y + v2.y + v3.y) * rinv;
        o.z = (v0.z + v1.z + v2.z + v3.z) * rinv;
        o.w = (v0.w + v1.w + v2.w + v3.w) * rinv;
        *(float4*)(op + f * 4) = o;
    }
}

extern "C" void kernel_launch(void* const* d_in, const int* in_sizes, int n_in,
                              void* d_out, int out_size, void* d_ws, size_t ws_size,
                              hipStream_t stream) {
    const float* X     = (const float*)d_in[0];
    const float* A     = (const float*)d_in[1];
    const float* W1    = (const float*)d_in[2];
    const float* W2    = (const float*)d_in[3];
    const float* alpha = (const float*)d_in[4];
    float* out = (float*)d_out;

    char* ws = (char*)d_ws;
    unsigned short* Gt = (unsigned short*)(ws);            // 2 MiB (tiled layout)
    float* lvp  = (float*)(ws + 2097152);                  // 64 KiB
    float* rvp  = (float*)(ws + 2097152 + 65536);          // 64 KiB
    float* pout = (float*)(ws + 2097152 + 131072);         // 4096*1088*4 = 17.8 MiB

    prep_kernel<<<256, 256, 0, stream>>>(X, W1, W2, alpha, Gt, lvp, rvp);
    attn_main<<<4096, 64, 0, stream>>>(A, Gt, lvp, rvp, pout);
    attn_reduce<<<256, 256, 0, stream>>>(pout, out);
}

// Round 8
// 157.138 us; speedup vs baseline: 1.3928x; 1.3498x over previous
//
#include <hip/hip_runtime.h>
#include <hip/hip_bf16.h>

typedef __attribute__((ext_vector_type(8))) short short8;
typedef __attribute__((ext_vector_type(4))) float floatx4;
typedef unsigned int u32;

#define NN 4096

static __device__ __forceinline__ unsigned f2bf_rne(float x) {
    union { float f; unsigned u; } v; v.f = x;
    unsigned r = v.u + 0x7fffu + ((v.u >> 16) & 1u);
    return r >> 16;
}
static __device__ __forceinline__ float bf2f(unsigned hi) {
    union { unsigned u; float f; } v; v.u = hi << 16; return v.f;
}

// ---- prep (fused wc, ROUND-0 VERBATIM): per-block computes Wc=W1@W2,
// w1*alpha; then G = X@Wc (bf16 hi/lo MFMA) -> Gt bf16 [b*64+c][4096] row-
// major; lv/rv fp32.
__global__ __launch_bounds__(256, 4)
void prep_kernel(const float* __restrict__ X,
                 const float* __restrict__ W1,
                 const float* __restrict__ W2,
                 const float* __restrict__ alpha,
                 unsigned short* __restrict__ Gt,
                 float* __restrict__ lv,
                 float* __restrict__ rv) {
    __shared__ __align__(16) char sm[53248];
    float* W1s  = (float*)sm;                 // [64][68]
    float* W2s  = (float*)(sm + 17408);       // [64][68]
    float* Wcst = (float*)(sm + 34816);       // Wc^T: [n][k] stride 68
    float* w1s  = (float*)(sm + 52224);       // [128]
    float* als  = (float*)(sm + 52736);       // [128]
    float* GsT  = (float*)sm;                 // epilogue reuse: [64][68]

    const int t = threadIdx.x;
    const int row0 = blockIdx.x * 64;         // flat b*N + n
    const int b = row0 >> 12, n0 = row0 & (NN - 1);
    const int w = t >> 6, lane = t & 63;
    const int m = lane & 15, q = lane >> 4;

    // issue X loads early (consumed much later)
    const int row = row0 + w * 16 + m;
    const float* xp = X + (size_t)row * 64;
    float4 x0 = *(const float4*)(xp + q * 8);
    float4 x1 = *(const float4*)(xp + q * 8 + 4);
    float4 x2 = *(const float4*)(xp + 32 + q * 8);
    float4 x3 = *(const float4*)(xp + 32 + q * 8 + 4);

    #pragma unroll
    for (int s = 0; s < 4; ++s) {
        int idx = s * 1024 + t * 4;
        int r = idx >> 6, cc = idx & 63;
        *(float4*)&W1s[r * 68 + cc] = *(const float4*)(W1 + idx);
        *(float4*)&W2s[r * 68 + cc] = *(const float4*)(W2 + idx);
    }
    if (t < 128) als[t] = alpha[t];
    __syncthreads();

    // Wc^T: thread (k = t>>2, nq = t&3) computes Wc[k][n], n in [nq*16, nq*16+16)
    {
        const int k = t >> 2, nq = t & 3;
        float acc[16];
        #pragma unroll
        for (int i = 0; i < 16; ++i) acc[i] = 0.f;
        for (int mm = 0; mm < 64; ++mm) {
            float w1v = W1s[k * 68 + mm];
            #pragma unroll
            for (int i = 0; i < 16; ++i)
                acc[i] += w1v * W2s[mm * 68 + nq * 16 + i];
        }
        #pragma unroll
        for (int i = 0; i < 16; ++i)
            Wcst[(nq * 16 + i) * 68 + k] = acc[i];
    }
    if (t < 64) {   // w1a = {W1@aL, W1@aR}
        float sl = 0.f, sr = 0.f;
        for (int cc2 = 0; cc2 < 64; ++cc2) {
            float wv = W1s[t * 68 + cc2];
            sl += wv * als[cc2];
            sr += wv * als[64 + cc2];
        }
        w1s[t] = sl; w1s[64 + t] = sr;
    }
    __syncthreads();

    const float xs[16] = {x0.x,x0.y,x0.z,x0.w, x1.x,x1.y,x1.z,x1.w,
                          x2.x,x2.y,x2.z,x2.w, x3.x,x3.y,x3.z,x3.w};

    // lv/rv fp32
    float pl = 0.f, pr = 0.f;
    #pragma unroll
    for (int ks = 0; ks < 2; ++ks)
        #pragma unroll
        for (int j = 0; j < 8; ++j) {
            int k = ks * 32 + q * 8 + j;
            float xv = xs[ks * 8 + j];
            pl += xv * w1s[k];
            pr += xv * w1s[64 + k];
        }
    pl += __shfl_xor(pl, 16, 64); pl += __shfl_xor(pl, 32, 64);
    pr += __shfl_xor(pr, 16, 64); pr += __shfl_xor(pr, 32, 64);
    if (q == 0) { lv[row] = pl; rv[row] = pr; }

    // bf16 hi/lo A-fragments
    short8 ah[2], al[2];
    #pragma unroll
    for (int ks = 0; ks < 2; ++ks)
        #pragma unroll
        for (int j = 0; j < 8; ++j) {
            float f = xs[ks * 8 + j];
            unsigned hb = f2bf_rne(f);
            float res = f - bf2f(hb);
            ah[ks][j] = (short)hb;
            al[ks][j] = (short)f2bf_rne(res);
        }

    // B-frags from Wcst
    short8 bfr[4][2];
    #pragma unroll
    for (int nt = 0; nt < 4; ++nt)
        #pragma unroll
        for (int ks = 0; ks < 2; ++ks) {
            const float* wp = &Wcst[(nt * 16 + m) * 68 + ks * 32 + q * 8];
            float4 w0 = *(const float4*)wp;
            float4 w1 = *(const float4*)(wp + 4);
            short8 bf;
            bf[0] = (short)f2bf_rne(w0.x); bf[1] = (short)f2bf_rne(w0.y);
            bf[2] = (short)f2bf_rne(w0.z); bf[3] = (short)f2bf_rne(w0.w);
            bf[4] = (short)f2bf_rne(w1.x); bf[5] = (short)f2bf_rne(w1.y);
            bf[6] = (short)f2bf_rne(w1.z); bf[7] = (short)f2bf_rne(w1.w);
            bfr[nt][ks] = bf;
        }

    floatx4 acc[4] = {{0,0,0,0},{0,0,0,0},{0,0,0,0},{0,0,0,0}};
    #pragma unroll
    for (int ks = 0; ks < 2; ++ks)
        #pragma unroll
        for (int nt = 0; nt < 4; ++nt) {
            acc[nt] = __builtin_amdgcn_mfma_f32_16x16x32_bf16(ah[ks], bfr[nt][ks], acc[nt], 0, 0, 0);
            acc[nt] = __builtin_amdgcn_mfma_f32_16x16x32_bf16(al[ks], bfr[nt][ks], acc[nt], 0, 0, 0);
        }

    __syncthreads();    // all Wcst/W1s reads done; sm@0 reused as GsT
    #pragma unroll
    for (int nt = 0; nt < 4; ++nt)
        #pragma unroll
        for (int rg = 0; rg < 4; ++rg)
            GsT[(nt * 16 + m) * 68 + w * 16 + q * 4 + rg] = acc[nt][rg];
    __syncthreads();
    unsigned* Gu = (unsigned*)Gt;
    #pragma unroll
    for (int it2 = 0; it2 < 8; ++it2) {
        int c2 = (t >> 5) + it2 * 8;
        int np = t & 31;
        unsigned lo = f2bf_rne(GsT[c2 * 68 + 2 * np]);
        unsigned hi = f2bf_rne(GsT[c2 * 68 + 2 * np + 1]);
        Gu[(((((size_t)(b * 64 + c2)) << 12) + n0) >> 1) + np] = lo | (hi << 16);
    }
}

// ---- attn v8 = round-0 structure + three proven deltas:
// (1) E generated IN-REGISTER in MFMA consumer layout (v4) -> Es staging,
//     transpose, and one barrier per chunk deleted;
// (2) VALU dsum (v4) -> ones-MFMA deleted;
// (3) the per-chunk barrier is lgkmcnt-ONLY (asm s_waitcnt lgkmcnt(0) +
//     raw s_barrier): publishes LDS writes cross-wave WITHOUT draining
//     vmcnt -> the reg-staged global prefetch (G chunk cc+2, A/rv depth-2)
//     stays in flight across barriers; the compiler's own COUNTED vmcnt
//     waits (before ds_write/use, loads issued ~1 chunk earlier) do the
//     pipelining. This removes round-0's 2x full-drain per chunk.
// G ring: 3 buffers; chunk cc reads buf[cc%3], publishes G(cc+1) into
// buf[(cc+1)%3] (last read 2 barriers earlier -> race-free).
__global__ __launch_bounds__(1024, 4)
void attn_kernel(const float* __restrict__ A,
                 const unsigned short* __restrict__ Gt,
                 const float* __restrict__ lv,
                 const float* __restrict__ rv,
                 float* __restrict__ out) {
    __shared__ __align__(16) char sm[61440];   // Gs[3 buf][4 grp][64*40] u16; epilogue red reuse
    unsigned short* Gs = (unsigned short*)sm;

    const int bx = blockIdx.x;
    const int i0 = (bx & 63) * 64;
    const int b  = bx >> 6;
    const int t = threadIdx.x;
    const int wave = t >> 6, lane = t & 63;
    const int grp = wave >> 2, wsub = wave & 3;
    const int m = lane & 15, q = lane >> 4;
    const int irE = wsub * 16 + m;             // consumer/E row
    const int irS = wsub * 16 + (lane >> 2);   // staging row (round-0 mapping)
    const int jseg = lane & 3;

    const float* aRow = A + (size_t)(i0 + irE) * NN + grp * 1024 + q * 8;
    const float* rvp  = rv + (size_t)b * NN + grp * 1024 + q * 8;
    const unsigned short* gRow = Gt + (((size_t)(b * 64 + irS)) << 12) + grp * 1024 + jseg * 8;

    const float li = lv[b * NN + i0 + irE] * 1.44269504f;   // fold log2e
    const float li001 = li * 0.01f;
    const bool diag_grp = ((i0 >> 10) == grp);
    const int jd = (i0 + irE) - grp * 1024;

    const int soff = irS * 40 + jseg * 8;      // staging offset within group tile
    unsigned short* GsG = Gs + grp * 2560;     // + buf*10240 selects ring buffer

    // prologue: G(0)->buf0; G(1)->sg; A/rv chunks 0 (E set) and 1 (O set)
    short8 sg = *(const short8*)(gRow);
    float4 a0E = *(const float4*)(aRow);
    float4 a1E = *(const float4*)(aRow + 4);
    float4 r0E = *(const float4*)(rvp);
    float4 r1E = *(const float4*)(rvp + 4);
    float4 a0O = *(const float4*)(aRow + 32);
    float4 a1O = *(const float4*)(aRow + 36);
    float4 r0O = *(const float4*)(rvp + 32);
    float4 r1O = *(const float4*)(rvp + 36);
    *(short8*)&GsG[soff] = sg;                 // buf0 = G(0)
    sg = *(const short8*)(gRow + 32);          // G(1)
    asm volatile("s_waitcnt lgkmcnt(0)" ::: "memory");
    __builtin_amdgcn_s_barrier();
    __builtin_amdgcn_sched_barrier(0);

    floatx4 acc0 = {0,0,0,0}, acc1 = {0,0,0,0}, acc2 = {0,0,0,0}, acc3 = {0,0,0,0};
    float dsum = 0.f;

    auto genE = [&](float4 a0, float4 a1, float4 r0, float4 r1, int chunk) -> short8 {
        float aa[8] = {a0.x, a0.y, a0.z, a0.w, a1.x, a1.y, a1.z, a1.w};
        if (diag_grp && ((jd >> 5) == chunk)) {            // adj diag := 1
            const int dd = jd - (chunk * 32 + q * 8);
            #pragma unroll
            for (int e = 0; e < 8; ++e) if (dd == e) aa[e] = 1.0f;
        }
        const float rr[8] = {r0.x, r0.y, r0.z, r0.w, r1.x, r1.y, r1.z, r1.w};
        unsigned up[8];
        #pragma unroll
        for (int e = 0; e < 8; ++e) {
            float s = fmaxf(li * rr[e], li001 * rr[e]);    // leaky(li*r)
            float ev = __builtin_amdgcn_exp2f(s) * aa[e];
            unsigned u = __float_as_uint(ev) + 0x8000u;
            up[e] = u;
            dsum += __uint_as_float(u & 0xffff0000u);      // den = same bf16 vals
        }
        union { unsigned u[4]; short8 s8; } cv;
        cv.u[0] = __builtin_amdgcn_perm(up[1], up[0], 0x07060302u);
        cv.u[1] = __builtin_amdgcn_perm(up[3], up[2], 0x07060302u);
        cv.u[2] = __builtin_amdgcn_perm(up[5], up[4], 0x07060302u);
        cv.u[3] = __builtin_amdgcn_perm(up[7], up[6], 0x07060302u);
        return cv.s8;
    };

    for (int cc = 0; cc < 32; cc += 2) {
        // ---- even chunk cc: read buf[cc%3], publish G(cc+1)->buf[(cc+1)%3] ----
        {
            *(short8*)&GsG[((cc + 1) % 3) * 10240 + soff] = sg;       // publish G(cc+1)
            { const int jn = (cc + 2 < 32) ? (cc + 2) * 32 : 0;       // fetch G(cc+2)
              sg = *(const short8*)(gRow + jn); }
            const short8 afr = genE(a0E, a1E, r0E, r1E, cc);
            { const int jn = (cc + 2 < 32) ? (cc + 2) * 32 : 0;       // reload E set <- cc+2
              a0E = *(const float4*)(aRow + jn);
              a1E = *(const float4*)(aRow + jn + 4);
              r0E = *(const float4*)(rvp + jn);
              r1E = *(const float4*)(rvp + jn + 4); }
            const unsigned short* rb = &GsG[(cc % 3) * 10240];
            const short8 b0 = *(const short8*)&rb[( m) * 40 + q * 8];
            const short8 b1 = *(const short8*)&rb[(16 + m) * 40 + q * 8];
            const short8 b2 = *(const short8*)&rb[(32 + m) * 40 + q * 8];
            const short8 b3 = *(const short8*)&rb[(48 + m) * 40 + q * 8];
            acc0 = __builtin_amdgcn_mfma_f32_16x16x32_bf16(afr, b0, acc0, 0, 0, 0);
            acc1 = __builtin_amdgcn_mfma_f32_16x16x32_bf16(afr, b1, acc1, 0, 0, 0);
            acc2 = __builtin_amdgcn_mfma_f32_16x16x32_bf16(afr, b2, acc2, 0, 0, 0);
            acc3 = __builtin_amdgcn_mfma_f32_16x16x32_bf16(afr, b3, acc3, 0, 0, 0);
            asm volatile("s_waitcnt lgkmcnt(0)" ::: "memory");        // ds ops only
            __builtin_amdgcn_s_barrier();                             // vmem stays in flight
            __builtin_amdgcn_sched_barrier(0);
        }
        // ---- odd chunk cc+1: read buf[(cc+1)%3], publish G(cc+2)->buf[(cc+2)%3] ----
        {
            *(short8*)&GsG[((cc + 2) % 3) * 10240 + soff] = sg;       // publish G(cc+2)
            { const int jn = (cc + 3 < 32) ? (cc + 3) * 32 : 0;       // fetch G(cc+3)
              sg = *(const short8*)(gRow + jn); }
            const short8 afr = genE(a0O, a1O, r0O, r1O, cc + 1);
            { const int jn = (cc + 3 < 32) ? (cc + 3) * 32 : 0;       // reload O set <- cc+3
              a0O = *(const float4*)(aRow + jn);
              a1O = *(const float4*)(aRow + jn + 4);
              r0O = *(const float4*)(rvp + jn);
              r1O = *(const float4*)(rvp + jn + 4); }
            const unsigned short* rb = &GsG[((cc + 1) % 3) * 10240];
            const short8 b0 = *(const short8*)&rb[( m) * 40 + q * 8];
            const short8 b1 = *(const short8*)&rb[(16 + m) * 40 + q * 8];
            const short8 b2 = *(const short8*)&rb[(32 + m) * 40 + q * 8];
            const short8 b3 = *(const short8*)&rb[(48 + m) * 40 + q * 8];
            acc0 = __builtin_amdgcn_mfma_f32_16x16x32_bf16(afr, b0, acc0, 0, 0, 0);
            acc1 = __builtin_amdgcn_mfma_f32_16x16x32_bf16(afr, b1, acc1, 0, 0, 0);
            acc2 = __builtin_amdgcn_mfma_f32_16x16x32_bf16(afr, b2, acc2, 0, 0, 0);
            acc3 = __builtin_amdgcn_mfma_f32_16x16x32_bf16(afr, b3, acc3, 0, 0, 0);
            asm volatile("s_waitcnt lgkmcnt(0)" ::: "memory");
            __builtin_amdgcn_s_barrier();
            __builtin_amdgcn_sched_barrier(0);
        }
    }

    // den: reduce over the 4 q-lanes of each row
    dsum += __shfl_xor(dsum, 16, 64);
    dsum += __shfl_xor(dsum, 32, 64);

    // ---- epilogue: two-pass cross-group reduction in LDS, divide, store ----
    __syncthreads();                           // full drain once; sm reused as red
    float* red = (float*)sm;                   // [2][64][68]; col 64 holds den
    const int il = t >> 4, c4 = t & 15;
    float4 osum = {0.f, 0.f, 0.f, 0.f};
    float dtot = 0.f;
    #pragma unroll
    for (int pass = 0; pass < 2; ++pass) {
        if ((grp >> 1) == pass) {
            float* rp_ = red + (grp & 1) * 4352;
            #pragma unroll
            for (int nt = 0; nt < 4; ++nt) {
                floatx4 av = nt == 0 ? acc0 : nt == 1 ? acc1 : nt == 2 ? acc2 : acc3;
                #pragma unroll
                for (int rg = 0; rg < 4; ++rg)
                    rp_[(wsub * 16 + q * 4 + rg) * 68 + nt * 16 + m] = av[rg];
            }
            if (q == 0) rp_[(wsub * 16 + m) * 68 + 64] = dsum;
        }
        __syncthreads();
        {
            float4 v0 = *(const float4*)&red[il * 68 + c4 * 4];
            float4 v1 = *(const float4*)&red[4352 + il * 68 + c4 * 4];
            osum.x += v0.x + v1.x; osum.y += v0.y + v1.y;
            osum.z += v0.z + v1.z; osum.w += v0.w + v1.w;
            dtot += red[il * 68 + 64] + red[4352 + il * 68 + 64];
        }
        __syncthreads();
    }
    const float rinv = 1.0f / dtot;
    float4 o;
    o.x = osum.x * rinv; o.y = osum.y * rinv;
    o.z = osum.z * rinv; o.w = osum.w * rinv;
    *(float4*)(out + (((size_t)(b * NN + i0 + il)) << 6) + c4 * 4) = o;
}

extern "C" void kernel_launch(void* const* d_in, const int* in_sizes, int n_in,
                              void* d_out, int out_size, void* d_ws, size_t ws_size,
                              hipStream_t stream) {
    const float* X     = (const float*)d_in[0];
    const float* A     = (const float*)d_in[1];
    const float* W1    = (const float*)d_in[2];
    const float* W2    = (const float*)d_in[3];
    const float* alpha = (const float*)d_in[4];
    float* out = (float*)d_out;

    char* ws = (char*)d_ws;
    unsigned short* Gt = (unsigned short*)(ws);            // 2 MiB (row-major)
    float* lvp = (float*)(ws + 2097152);                   // 64 KiB
    float* rvp = (float*)(ws + 2097152 + 65536);           // 64 KiB

    prep_kernel<<<256, 256, 0, stream>>>(X, W1, W2, alpha, Gt, lvp, rvp);
    attn_kernel<<<256, 1024, 0, stream>>>(A, Gt, lvp, rvp, out);
}